// Round 13
// baseline (266.381 us; speedup 1.0000x reference)
//
#include <hip/hip_runtime.h>

#define EPSF 1e-6f

typedef _Float16 f16x8 __attribute__((ext_vector_type(8)));
typedef _Float16 f16x4 __attribute__((ext_vector_type(4)));
typedef float    f32x4 __attribute__((ext_vector_type(4)));

#define GLL16(gp, lp) __builtin_amdgcn_global_load_lds( \
    (const __attribute__((address_space(1))) void*)(gp), \
    (__attribute__((address_space(3))) void*)(lp), 16, 0, 0)

// ---------------- f32 -> f16 convert: x, y, WQ, WK in ONE dispatch ----------------
// ranges (8-elem items): [0,nxy) x->xb | [nxy,2nxy) y->yb | [2nxy,2nxy+nw) WQ | [+nw) WK
__global__ __launch_bounds__(256) void cvt4_f16(const float* __restrict__ x,
                                                _Float16* __restrict__ xb,
                                                const float* __restrict__ y,
                                                _Float16* __restrict__ yb,
                                                const float* __restrict__ WQ,
                                                const float* __restrict__ WK,
                                                _Float16* __restrict__ WQKb,
                                                int nxy, int nw) {
    int idx = blockIdx.x * 256 + threadIdx.x;
    const float* in; _Float16* out;
    if (idx < nxy)                { in = x;  out = xb;  }
    else if (idx < 2 * nxy)       { in = y;  out = yb;  idx -= nxy; }
    else if (idx < 2 * nxy + nw)  { in = WQ; out = WQKb; idx -= 2 * nxy; }
    else                          { in = WK; out = WQKb + (size_t)nw * 8; idx -= 2 * nxy + nw; }
    const float4* p = (const float4*)in + (size_t)idx * 2;
    float4 a = p[0], b = p[1];
    f16x8 o;
    o[0] = (_Float16)a.x; o[1] = (_Float16)a.y; o[2] = (_Float16)a.z; o[3] = (_Float16)a.w;
    o[4] = (_Float16)b.x; o[5] = (_Float16)b.y; o[6] = (_Float16)b.z; o[7] = (_Float16)b.w;
    *(f16x8*)(out + (size_t)idx * 8) = o;
}

// ---------------- prep: block-diag omega^T (f16) + folded biases (interleaved) + ksum zero ----------------
__global__ __launch_bounds__(256) void prep_all(const float* __restrict__ omega,
                                                const float* __restrict__ bQ,
                                                const float* __restrict__ bK,
                                                const float* __restrict__ bV,
                                                _Float16* __restrict__ obdT,
                                                float* __restrict__ bQf,
                                                float* __restrict__ bkv,
                                                float* __restrict__ ksum) {
    int idx = blockIdx.x * 256 + threadIdx.x;   // over 1M
    int c = idx >> 10, k = idx & 1023;
    float v = ((c >> 6) == (k >> 6)) ? omega[(k & 63) * 64 + (c & 63)] : 0.f;
    obdT[idx] = (_Float16)v;
    if (idx < 4096) ksum[idx] = 0.f;            // zeroed every call (atomics target)
    if (idx < 1024) {
        int h = idx >> 6, e = idx & 63;
        float sq = 0.f, sk = 0.f;
        for (int d = 0; d < 64; d++) {
            float o = omega[d * 64 + e];
            sq += bQ[h * 64 + d] * o;
            sk += bK[h * 64 + d] * o;
        }
        bQf[idx] = sq;
        bkv[h * 128 + e] = sk;                  // interleaved per head: [K(64)|V(64)]
        bkv[h * 128 + 64 + e] = bV[idx];
    }
}

// ---------------- transpose 1024x1024 f32 -> f16, both WV (V-interleave) and WO in one dispatch ----------------
__global__ __launch_bounds__(256) void transpose2_cvt(const float* __restrict__ inV,
                                                      _Float16* __restrict__ outV,
                                                      const float* __restrict__ inO,
                                                      _Float16* __restrict__ outO) {
    __shared__ float tile[64][65];
    const int t = threadIdx.x;
    const int k0 = blockIdx.x * 64, n0 = blockIdx.y * 64;
    const int vmode = (blockIdx.z == 0);
    const float* in = vmode ? inV : inO;
    _Float16* out = vmode ? outV : outO;
#pragma unroll
    for (int j = 0; j < 16; j++) {
        int idx = j * 256 + t; int r = idx >> 6, c = idx & 63;
        tile[r][c] = in[(size_t)(k0 + r) * 1024 + n0 + c];
    }
    __syncthreads();
#pragma unroll
    for (int j = 0; j < 16; j++) {
        int idx = j * 256 + t; int rn = idx >> 6, ck = idx & 63;
        int rowo = n0 + rn;
        if (vmode) rowo = ((rowo >> 6) << 7) + 64 + (rowo & 63);
        out[(size_t)rowo * 1024 + k0 + ck] = (_Float16)tile[ck][rn];
    }
}

// ---------------- fold GEMM (m97 128^2): [WQ;WK](2048x1024) @ obdT^T ----------------
__global__ __launch_bounds__(256) void gemm_fold(const _Float16* __restrict__ A,
                                                 const _Float16* __restrict__ Bt,
                                                 _Float16* __restrict__ out0,
                                                 _Float16* __restrict__ out1) {
    const int K = 1024;
    __shared__ __align__(16) _Float16 Asm[128 * 32];
    __shared__ __align__(16) _Float16 Bsm[128 * 32];
    const int t = threadIdx.x, lane = t & 63, w = t >> 6;
    const int bm = blockIdx.y * 128, bn = blockIdx.x * 128;
    const int wm = (w >> 1) * 64, wn = (w & 1) * 64;
    const int r15 = lane & 15, slog = lane >> 4;

    int aoff[4], boff[4];
#pragma unroll
    for (int m = 0; m < 4; m++) {
        int ra = wm + m * 16 + r15;
        aoff[m] = ra * 32 + (slog ^ ((ra >> 1) & 3)) * 8;
        int rb = wn + m * 16 + r15;
        boff[m] = rb * 32 + (slog ^ ((rb >> 1) & 3)) * 8;
    }
    f32x4 acc[4][4];
#pragma unroll
    for (int m = 0; m < 4; m++)
#pragma unroll
        for (int n = 0; n < 4; n++) acc[m][n] = (f32x4){0.f, 0.f, 0.f, 0.f};

    for (int kt = 0; kt < K; kt += 32) {
        __syncthreads();
#pragma unroll
        for (int i = 0; i < 2; i++) {
            int seg = i * 256 + w * 64 + lane;
            int r = seg >> 2, sp = seg & 3;
            int sg = sp ^ ((r >> 1) & 3);
            GLL16(A  + (size_t)(bm + r) * K + kt + sg * 8, Asm + (size_t)(i * 256 + w * 64) * 8);
            GLL16(Bt + (size_t)(bn + r) * K + kt + sg * 8, Bsm + (size_t)(i * 256 + w * 64) * 8);
        }
        __syncthreads();
        f16x8 av[4], bv[4];
#pragma unroll
        for (int m = 0; m < 4; m++) av[m] = *(const f16x8*)(Asm + aoff[m]);
#pragma unroll
        for (int n = 0; n < 4; n++) bv[n] = *(const f16x8*)(Bsm + boff[n]);
#pragma unroll
        for (int m = 0; m < 4; m++)
#pragma unroll
            for (int n = 0; n < 4; n++)
                acc[m][n] = __builtin_amdgcn_mfma_f32_16x16x32_f16(av[m], bv[n], acc[m][n], 0, 0, 0);
    }

#pragma unroll
    for (int m = 0; m < 4; m++) {
        int row0 = bm + wm + m * 16 + slog * 4;
        int l = row0 & 1023;
#pragma unroll
        for (int n = 0; n < 4; n++) {
            int colg = bn + wn + n * 16 + r15;
            f16x4 p;
#pragma unroll
            for (int j = 0; j < 4; j++) p[j] = (_Float16)acc[m][n][j];
            if (row0 < 1024) {
                *(f16x4*)(out0 + (size_t)colg * 1024 + l) = p;
            } else {
                int rr = ((colg >> 6) << 7) + (colg & 63);   // K-interleave
                *(f16x4*)(out1 + (size_t)rr * 1024 + l) = p;
            }
        }
    }
}

// ---------------- big GEMM: 256x256 tile, BK=32 slab, 4-slab LDS ring, counted vmcnt (R9-exact core) ----------------
// EPI: 2 = linear -> f32 [M][N], Bt batched per 4096 rows
//      4 = relu+eps + fused divide by (qphi . ksum) -> f16 out0; out1 = ksum
//      5 = KV projection: phi(K) + fused kv mini-GEMM -> kvpart [head][16][64][64] (d,e) + ksum atomics
template<int EPI>
__global__ __launch_bounds__(512, 2) void gemm256(const _Float16* __restrict__ A,
                                                  const _Float16* __restrict__ Bt,
                                                  const float* __restrict__ bias,
                                                  void* __restrict__ out0,
                                                  void* __restrict__ out1,
                                                  float* __restrict__ ksum,
                                                  int M, int N, int K, int nbn) {
    __shared__ __align__(16) char lds[131072];
    const int t = threadIdx.x, lane = t & 63, w = t >> 6;
    const int nwg = gridDim.x;
    const int f = (blockIdx.x & 7) * (nwg >> 3) + (blockIdx.x >> 3);   // bijective XCD swizzle
    const int bm = (f / nbn) * 256, bn = (f % nbn) * 256;
    const int wm = (w & 1) * 128, wn = (w >> 1) * 64;
    const int r15 = lane & 15, hi = lane >> 4;
    const int srow = lane >> 2, sp = lane & 3;     // staging: 16 rows/gll, 4 slots/row
    const _Float16* BtU = (EPI == 2) ? Bt + ((size_t)(bm >> 12) << 20) : Bt;  // per-batch B

    int aoff[8], boff[4];
#pragma unroll
    for (int m = 0; m < 8; m++) {
        int r = wm + m * 16 + r15;
        aoff[m] = r * 64 + (((hi + (r >> 1)) & 3) << 4);
    }
#pragma unroll
    for (int n = 0; n < 4; n++) {
        int r = wn + n * 16 + r15;
        boff[n] = r * 64 + (((hi + (r >> 1)) & 3) << 4);
    }

    f32x4 acc[8][4];
#pragma unroll
    for (int m = 0; m < 8; m++)
#pragma unroll
        for (int n = 0; n < 4; n++) acc[m][n] = (f32x4){0.f, 0.f, 0.f, 0.f};

    auto stage = [&](int s) {
        char* base = lds + (s & 3) * 32768;
        int kt = s * 32;
#pragma unroll
        for (int p = 0; p < 2; p++) {
            int row = w * 32 + p * 16 + srow;
            int sg = (sp - ((row >> 1) & 3)) & 3;   // pre-swizzled global slot
            GLL16(A   + (size_t)(bm + row) * K + kt + sg * 8, base + w * 2048 + p * 1024);
            GLL16(BtU + (size_t)(bn + row) * K + kt + sg * 8, base + 16384 + w * 2048 + p * 1024);
        }
    };

    const int NS = K >> 5;
    stage(0); stage(1); stage(2);
    for (int s = 0; s < NS; ++s) {
        if (s + 2 < NS)      asm volatile("s_waitcnt vmcnt(8)" ::: "memory");
        else if (s + 1 < NS) asm volatile("s_waitcnt vmcnt(4)" ::: "memory");
        else                 asm volatile("s_waitcnt vmcnt(0)" ::: "memory");
        asm volatile("s_barrier" ::: "memory");
        if (s + 3 < NS) stage(s + 3);               // slot (s-1)&3: reads done last slab
        const char* La = lds + (s & 3) * 32768;
        const char* Lb = La + 16384;
        f16x8 bv[4];
#pragma unroll
        for (int n = 0; n < 4; n++) bv[n] = *(const f16x8*)(Lb + boff[n]);
        f16x8 av[8];
#pragma unroll
        for (int m = 0; m < 8; m++) av[m] = *(const f16x8*)(La + aoff[m]);
        __builtin_amdgcn_s_setprio(1);
#pragma unroll
        for (int m = 0; m < 8; m++)
#pragma unroll
            for (int n = 0; n < 4; n++)
                acc[m][n] = __builtin_amdgcn_mfma_f32_16x16x32_f16(av[m], bv[n], acc[m][n], 0, 0, 0);
        __builtin_amdgcn_s_setprio(0);
    }

    if (EPI == 5) {
        // cols are head-interleaved [K_h|V_h]; quadrant q = w>>1: 0=K(g0) 1=V(g0) 2=K(g0+1) 3=V(g0+1)
        const int q = w >> 1;
        const bool isK = !(q & 1);
        const int nb = bm >> 12;
        const int g0 = bn >> 7;                 // first local head of this block's pair
        __syncthreads();                        // all slab reads done before LDS reuse
        char* LT = lds + q * 32768;             // tile [64 rows][512 B] (l-major within row)
        float cs[4] = {0.f, 0.f, 0.f, 0.f};
#pragma unroll
        for (int m = 0; m < 8; m++)
#pragma unroll
            for (int n = 0; n < 4; n++) {
                int dd = n * 16 + r15;
                float bs = bias[bn + wn + dd];
                f16x4 pk;
#pragma unroll
                for (int j = 0; j < 4; j++) {
                    float xv = acc[m][n][j] + bs;
                    if (isK) { xv = fmaxf(xv, 0.f) + EPSF; cs[n] += xv; }
                    pk[j] = (_Float16)xv;
                }
                int l2 = (wm + m * 16 + hi * 4) * 2;
                *(f16x4*)(LT + dd * 512 + (l2 ^ ((dd & 7) << 4))) = pk;
            }
        if (isK) {   // fused ksum: this wave covers 128 l-rows of head g0+(q>>1)
#pragma unroll
            for (int n = 0; n < 4; n++) {
                cs[n] += __shfl_xor(cs[n], 16, 64);
                cs[n] += __shfl_xor(cs[n], 32, 64);
            }
            if (hi == 0) {
#pragma unroll
                for (int n = 0; n < 4; n++)
                    atomicAdd(ksum + (size_t)(nb * 16 + g0 + (q >> 1)) * 64 + n * 16 + r15, cs[n]);
            }
        }
        __syncthreads();
        // mini-GEMM kv[d][e] = sum_l Kphi[l][d]*V[l][e] over this block's 256 rows.
        // 32 output 16x16 tiles (2 heads x 4x4); wave w owns tiles w*4 .. w*4+3.
        f32x4 kva[4];
#pragma unroll
        for (int i = 0; i < 4; i++) kva[i] = (f32x4){0.f, 0.f, 0.f, 0.f};
#pragma unroll
        for (int i = 0; i < 4; i++) {
            int tt = w * 4 + i;
            int hl = tt >> 4, dg = (tt >> 2) & 3, eg = tt & 3;
            const char* KT = lds + (hl * 2) * 32768;
            const char* VT = lds + (hl * 2 + 1) * 32768;
            int d = dg * 16 + r15, e = eg * 16 + r15;
#pragma unroll
            for (int ks = 0; ks < 8; ks++) {
                int l2 = (ks * 32 + hi * 8) * 2;
                f16x8 ka = *(const f16x8*)(KT + d * 512 + (l2 ^ ((d & 7) << 4)));
                f16x8 vb = *(const f16x8*)(VT + e * 512 + (l2 ^ ((e & 7) << 4)));
                kva[i] = __builtin_amdgcn_mfma_f32_16x16x32_f16(ka, vb, kva[i], 0, 0, 0);
            }
        }
        const int chunk = (bm >> 8) & 15;
        float* kvp = (float*)out0;
#pragma unroll
        for (int i = 0; i < 4; i++) {
            int tt = w * 4 + i;
            int hl = tt >> 4, dg = (tt >> 2) & 3, eg = tt & 3;
            float* dst = kvp + ((size_t)(nb * 16 + g0 + hl) * 16 + chunk) * 4096;
#pragma unroll
            for (int j = 0; j < 4; j++)
                dst[(dg * 16 + hi * 4 + j) * 64 + eg * 16 + r15] = kva[i][j];
        }
    } else if (EPI == 4) {
        // relu+eps, then divide by den = qphi . ksum[head] (wave owns one head's 64 cols)
        const int headg = (bm >> 12) * 16 + ((bn + wn) >> 6);
        const float* ks = (const float*)out1;
        float ksn[4];
#pragma unroll
        for (int n = 0; n < 4; n++) ksn[n] = ks[(size_t)headg * 64 + n * 16 + r15];
        _Float16* C = (_Float16*)out0;
#pragma unroll
        for (int m = 0; m < 8; m++) {
            int row0 = bm + wm + m * 16 + hi * 4;
            float qv[4][4], dp[4] = {0.f, 0.f, 0.f, 0.f};
#pragma unroll
            for (int n = 0; n < 4; n++) {
                int colg = bn + wn + n * 16 + r15;
                float bs = bias[colg];
#pragma unroll
                for (int j = 0; j < 4; j++) {
                    float xv = fmaxf(acc[m][n][j] + bs, 0.f) + EPSF;
                    qv[n][j] = xv;
                    dp[j] += xv * ksn[n];
                }
            }
#pragma unroll
            for (int j = 0; j < 4; j++) {       // reduce over the 16 r15 lanes
                dp[j] += __shfl_xor(dp[j], 1, 64);
                dp[j] += __shfl_xor(dp[j], 2, 64);
                dp[j] += __shfl_xor(dp[j], 4, 64);
                dp[j] += __shfl_xor(dp[j], 8, 64);
                dp[j] = 4096.0f * __builtin_amdgcn_rcpf(dp[j]);
            }
#pragma unroll
            for (int n = 0; n < 4; n++) {
                int colg = bn + wn + n * 16 + r15;
#pragma unroll
                for (int j = 0; j < 4; j++)
                    C[(size_t)(row0 + j) * N + colg] = (_Float16)(qv[n][j] * dp[j]);
            }
        }
    } else {
#pragma unroll
        for (int m = 0; m < 8; m++) {
            int row0 = bm + wm + m * 16 + hi * 4;
#pragma unroll
            for (int n = 0; n < 4; n++) {
                int colg = bn + wn + n * 16 + r15;
                float bs = bias ? bias[colg] : 0.f;
#pragma unroll
                for (int j = 0; j < 4; j++)
                    ((float*)out0)[(size_t)(row0 + j) * N + colg] = acc[m][n][j] + bs;
            }
        }
    }
}

// ---------------- W2t[b][j][hl*64+d] = (1/4096) sum_e Wot[j][hl*64+e] * kv[gh][d][e] ----------------
// kvred fused: each block reduces the 16 L3-resident chunks itself.
// kv layout is [d][e]; store TRANSPOSED into kvL so kvL[e][d] = kv[d][e].
__global__ __launch_bounds__(256) void w2t_kernel(const _Float16* __restrict__ Wot,
                                                  const float* __restrict__ kvpart,
                                                  _Float16* __restrict__ W2t) {
    const int t = threadIdx.x;
    const int jb = blockIdx.x;      // 0..7 (128 j-rows each)
    const int gh = blockIdx.y;      // 0..63 global head
    const int b = gh >> 4, hl = gh & 15;
    __shared__ float kvL[64][65];
    const float* kp = kvpart + (size_t)gh * 16 * 4096;
#pragma unroll
    for (int i = 0; i < 16; i++) {
        int idx = i * 256 + t;
        float s = 0.f;
#pragma unroll
        for (int c = 0; c < 16; c++) s += kp[c * 4096 + idx];
        kvL[idx & 63][idx >> 6] = s;   // kvL[e][d] = kv[d][e]
    }
    __syncthreads();
    const int j = jb * 128 + (t >> 1);
    const int d0 = (t & 1) * 32;
    const _Float16* wr = Wot + (size_t)j * 1024 + hl * 64;
    float wv[64];
#pragma unroll
    for (int i = 0; i < 8; i++) {
        f16x8 v = *(const f16x8*)(wr + i * 8);
#pragma unroll
        for (int k = 0; k < 8; k++) wv[i * 8 + k] = (float)v[k];
    }
    _Float16* outp = W2t + ((size_t)b << 20) + (size_t)j * 1024 + hl * 64 + d0;
#pragma unroll
    for (int d = 0; d < 32; d++) {
        float s = 0.f;
#pragma unroll
        for (int e = 0; e < 64; e++) s += wv[e] * kvL[e][d0 + d];
        outp[d] = (_Float16)(s * (1.0f / 4096.0f));
    }
}

// ------------------------------------------------------------------------------------
extern "C" void kernel_launch(void* const* d_in, const int* in_sizes, int n_in,
                              void* d_out, int out_size, void* d_ws, size_t ws_size,
                              hipStream_t stream) {
    (void)in_sizes; (void)n_in; (void)out_size; (void)ws_size;
    const float* x     = (const float*)d_in[0];
    const float* y     = (const float*)d_in[1];
    const float* WQ    = (const float*)d_in[2];
    const float* bQ    = (const float*)d_in[3];
    const float* WK    = (const float*)d_in[4];
    const float* bK    = (const float*)d_in[5];
    const float* WV    = (const float*)d_in[6];
    const float* bV    = (const float*)d_in[7];
    const float* WO    = (const float*)d_in[8];
    const float* bO    = (const float*)d_in[9];
    const float* omega = (const float*)d_in[10];

    char* ws = (char*)d_ws;
    size_t off = 0;
    auto alloc = [&](size_t bytes) { void* p = ws + off; off += (bytes + 255) & ~(size_t)255; return p; };
    const size_t BIG = (size_t)16384 * 1024 * 2;    // 32 MiB f16
    _Float16* xb    = (_Float16*)alloc(BIG);
    _Float16* yb    = (_Float16*)alloc(BIG);
    _Float16* WQKb  = (_Float16*)alloc((size_t)2048 * 1024 * 2);  // stacked WQ;WK f16
    _Float16* obdT  = (_Float16*)alloc(1024 * 1024 * 2);
    _Float16* Wqt   = (_Float16*)alloc(1024 * 1024 * 2);
    _Float16* Wkvt  = (_Float16*)alloc((size_t)2048 * 1024 * 2);  // interleaved rows h*128+[K|V]
    _Float16* Wot   = (_Float16*)alloc(1024 * 1024 * 2);
    _Float16* W2t   = (_Float16*)alloc((size_t)4 * 1024 * 1024 * 2);  // per-batch folded kv@WO (^T)
    float*    bQf   = (float*)alloc(1024 * 4);
    float*    bkv   = (float*)alloc(2048 * 4);
    _Float16* U2    = (_Float16*)alloc(BIG);
    float*    kvpart= (float*)alloc((size_t)64 * 16 * 4096 * 4);  // [head][chunk=16][64][64] (d,e)
    float*    ksum  = (float*)alloc((size_t)64 * 64 * 4);

    // 1. precision converts: x, y, WQ, WK all in one dispatch
    //    nxy = 2097152 items, nw = 131072 items -> total 4456448 / 256 = 17408 blocks
    cvt4_f16<<<17408, 256, 0, stream>>>(x, xb, y, yb, WQ, WK, WQKb,
                                        16384 * 1024 / 8, 1024 * 1024 / 8);
    // 2. omega block-diag + interleaved bias folds + ksum zero; both weight transposes in one dispatch
    prep_all<<<4096, 256, 0, stream>>>(omega, bQ, bK, bV, obdT, bQf, bkv, ksum);
    transpose2_cvt<<<dim3(16, 16, 2), 256, 0, stream>>>(WV, Wkvt, WO, Wot);
    // 3. fold omega into WQ/WK (out1 = K-interleaved rows of Wkvt)
    gemm_fold<<<dim3(8, 16), 256, 0, stream>>>(WQKb, obdT, Wqt, Wkvt);
    // 4. K|V projection with fused phi + in-epilogue kv mini-GEMM + ksum atomics
    gemm256<5><<<512, 512, 0, stream>>>(yb, Wkvt, bkv, kvpart, nullptr, ksum, 16384, 2048, 1024, 8);
    // 5. fold kv into WO (per batch, scaled 1/4096; chunk reduce fused in)
    w2t_kernel<<<dim3(8, 64), 256, 0, stream>>>(Wot, kvpart, W2t);
    // 6. Q projection with fused phi + divide -> U2 = qphi*4096/den
    gemm256<4><<<256, 512, 0, stream>>>(xb, Wqt, bQf, U2, ksum, nullptr, 16384, 1024, 1024, 4);
    // 7. output projection: out = U2 @ W2t(batch)^T + bO
    gemm256<2><<<256, 512, 0, stream>>>(U2, W2t, bO, d_out, nullptr, nullptr, 16384, 1024, 1024, 4);
}

// Round 14
// 257.625 us; speedup vs baseline: 1.0340x; 1.0340x over previous
//
#include <hip/hip_runtime.h>

#define EPSF 1e-6f

typedef _Float16 f16x8 __attribute__((ext_vector_type(8)));
typedef _Float16 f16x4 __attribute__((ext_vector_type(4)));
typedef float    f32x4 __attribute__((ext_vector_type(4)));

#define GLL16(gp, lp) __builtin_amdgcn_global_load_lds( \
    (const __attribute__((address_space(1))) void*)(gp), \
    (__attribute__((address_space(3))) void*)(lp), 16, 0, 0)

// ---------------- f32 -> f16 convert: x, y, WQ, WK in ONE dispatch ----------------
// ranges (8-elem items): [0,nxy) x->xb | [nxy,2nxy) y->yb | [2nxy,2nxy+nw) WQ | [+nw) WK
__global__ __launch_bounds__(256) void cvt4_f16(const float* __restrict__ x,
                                                _Float16* __restrict__ xb,
                                                const float* __restrict__ y,
                                                _Float16* __restrict__ yb,
                                                const float* __restrict__ WQ,
                                                const float* __restrict__ WK,
                                                _Float16* __restrict__ WQKb,
                                                int nxy, int nw) {
    int idx = blockIdx.x * 256 + threadIdx.x;
    const float* in; _Float16* out;
    if (idx < nxy)                { in = x;  out = xb;  }
    else if (idx < 2 * nxy)       { in = y;  out = yb;  idx -= nxy; }
    else if (idx < 2 * nxy + nw)  { in = WQ; out = WQKb; idx -= 2 * nxy; }
    else                          { in = WK; out = WQKb + (size_t)nw * 8; idx -= 2 * nxy + nw; }
    const float4* p = (const float4*)in + (size_t)idx * 2;
    float4 a = p[0], b = p[1];
    f16x8 o;
    o[0] = (_Float16)a.x; o[1] = (_Float16)a.y; o[2] = (_Float16)a.z; o[3] = (_Float16)a.w;
    o[4] = (_Float16)b.x; o[5] = (_Float16)b.y; o[6] = (_Float16)b.z; o[7] = (_Float16)b.w;
    *(f16x8*)(out + (size_t)idx * 8) = o;
}

// ---------------- prep: block-diag omega^T (f16) + folded biases (interleaved) + ksum zero ----------------
__global__ __launch_bounds__(256) void prep_all(const float* __restrict__ omega,
                                                const float* __restrict__ bQ,
                                                const float* __restrict__ bK,
                                                const float* __restrict__ bV,
                                                _Float16* __restrict__ obdT,
                                                float* __restrict__ bQf,
                                                float* __restrict__ bkv,
                                                float* __restrict__ ksum) {
    int idx = blockIdx.x * 256 + threadIdx.x;   // over 1M
    int c = idx >> 10, k = idx & 1023;
    float v = ((c >> 6) == (k >> 6)) ? omega[(k & 63) * 64 + (c & 63)] : 0.f;
    obdT[idx] = (_Float16)v;
    if (idx < 4096) ksum[idx] = 0.f;            // zeroed every call (atomics target)
    if (idx < 1024) {
        int h = idx >> 6, e = idx & 63;
        float sq = 0.f, sk = 0.f;
        for (int d = 0; d < 64; d++) {
            float o = omega[d * 64 + e];
            sq += bQ[h * 64 + d] * o;
            sk += bK[h * 64 + d] * o;
        }
        bQf[idx] = sq;
        bkv[h * 128 + e] = sk;                  // interleaved per head: [K(64)|V(64)]
        bkv[h * 128 + 64 + e] = bV[idx];
    }
}

// ---------------- transpose 1024x1024 f32 -> f16, both WV (V-interleave) and WO in one dispatch ----------------
__global__ __launch_bounds__(256) void transpose2_cvt(const float* __restrict__ inV,
                                                      _Float16* __restrict__ outV,
                                                      const float* __restrict__ inO,
                                                      _Float16* __restrict__ outO) {
    __shared__ float tile[64][65];
    const int t = threadIdx.x;
    const int k0 = blockIdx.x * 64, n0 = blockIdx.y * 64;
    const int vmode = (blockIdx.z == 0);
    const float* in = vmode ? inV : inO;
    _Float16* out = vmode ? outV : outO;
#pragma unroll
    for (int j = 0; j < 16; j++) {
        int idx = j * 256 + t; int r = idx >> 6, c = idx & 63;
        tile[r][c] = in[(size_t)(k0 + r) * 1024 + n0 + c];
    }
    __syncthreads();
#pragma unroll
    for (int j = 0; j < 16; j++) {
        int idx = j * 256 + t; int rn = idx >> 6, ck = idx & 63;
        int rowo = n0 + rn;
        if (vmode) rowo = ((rowo >> 6) << 7) + 64 + (rowo & 63);
        out[(size_t)rowo * 1024 + k0 + ck] = (_Float16)tile[ck][rn];
    }
}

// ---------------- fold GEMM (m97 128^2): [WQ;WK](2048x1024) @ obdT^T ----------------
__global__ __launch_bounds__(256) void gemm_fold(const _Float16* __restrict__ A,
                                                 const _Float16* __restrict__ Bt,
                                                 _Float16* __restrict__ out0,
                                                 _Float16* __restrict__ out1) {
    const int K = 1024;
    __shared__ __align__(16) _Float16 Asm[128 * 32];
    __shared__ __align__(16) _Float16 Bsm[128 * 32];
    const int t = threadIdx.x, lane = t & 63, w = t >> 6;
    const int bm = blockIdx.y * 128, bn = blockIdx.x * 128;
    const int wm = (w >> 1) * 64, wn = (w & 1) * 64;
    const int r15 = lane & 15, slog = lane >> 4;

    int aoff[4], boff[4];
#pragma unroll
    for (int m = 0; m < 4; m++) {
        int ra = wm + m * 16 + r15;
        aoff[m] = ra * 32 + (slog ^ ((ra >> 1) & 3)) * 8;
        int rb = wn + m * 16 + r15;
        boff[m] = rb * 32 + (slog ^ ((rb >> 1) & 3)) * 8;
    }
    f32x4 acc[4][4];
#pragma unroll
    for (int m = 0; m < 4; m++)
#pragma unroll
        for (int n = 0; n < 4; n++) acc[m][n] = (f32x4){0.f, 0.f, 0.f, 0.f};

    for (int kt = 0; kt < K; kt += 32) {
        __syncthreads();
#pragma unroll
        for (int i = 0; i < 2; i++) {
            int seg = i * 256 + w * 64 + lane;
            int r = seg >> 2, sp = seg & 3;
            int sg = sp ^ ((r >> 1) & 3);
            GLL16(A  + (size_t)(bm + r) * K + kt + sg * 8, Asm + (size_t)(i * 256 + w * 64) * 8);
            GLL16(Bt + (size_t)(bn + r) * K + kt + sg * 8, Bsm + (size_t)(i * 256 + w * 64) * 8);
        }
        __syncthreads();
        f16x8 av[4], bv[4];
#pragma unroll
        for (int m = 0; m < 4; m++) av[m] = *(const f16x8*)(Asm + aoff[m]);
#pragma unroll
        for (int n = 0; n < 4; n++) bv[n] = *(const f16x8*)(Bsm + boff[n]);
#pragma unroll
        for (int m = 0; m < 4; m++)
#pragma unroll
            for (int n = 0; n < 4; n++)
                acc[m][n] = __builtin_amdgcn_mfma_f32_16x16x32_f16(av[m], bv[n], acc[m][n], 0, 0, 0);
    }

#pragma unroll
    for (int m = 0; m < 4; m++) {
        int row0 = bm + wm + m * 16 + slog * 4;
        int l = row0 & 1023;
#pragma unroll
        for (int n = 0; n < 4; n++) {
            int colg = bn + wn + n * 16 + r15;
            f16x4 p;
#pragma unroll
            for (int j = 0; j < 4; j++) p[j] = (_Float16)acc[m][n][j];
            if (row0 < 1024) {
                *(f16x4*)(out0 + (size_t)colg * 1024 + l) = p;
            } else {
                int rr = ((colg >> 6) << 7) + (colg & 63);   // K-interleave
                *(f16x4*)(out1 + (size_t)rr * 1024 + l) = p;
            }
        }
    }
}

// ---------------- big GEMM: 256x256 tile, BK=32 slab, 4-slab LDS ring, counted vmcnt (R9-exact core) ----------------
// EPI: 2 = linear -> f32 [M][N], Bt batched per 4096 rows
//      4 = relu+eps + fused divide by (qphi . ksum) -> f16 out0; out1 = ksum
//      5 = KV projection: phi(K) + fused kv mini-GEMM -> kvpart [head][16][64][64] (d,e) + ksum atomics
template<int EPI>
__global__ __launch_bounds__(512, 2) void gemm256(const _Float16* __restrict__ A,
                                                  const _Float16* __restrict__ Bt,
                                                  const float* __restrict__ bias,
                                                  void* __restrict__ out0,
                                                  void* __restrict__ out1,
                                                  float* __restrict__ ksum,
                                                  int M, int N, int K, int nbn) {
    __shared__ __align__(16) char lds[131072];
    const int t = threadIdx.x, lane = t & 63, w = t >> 6;
    const int nwg = gridDim.x;
    const int f = (blockIdx.x & 7) * (nwg >> 3) + (blockIdx.x >> 3);   // bijective XCD swizzle
    const int bm = (f / nbn) * 256, bn = (f % nbn) * 256;
    const int wm = (w & 1) * 128, wn = (w >> 1) * 64;
    const int r15 = lane & 15, hi = lane >> 4;
    const int srow = lane >> 2, sp = lane & 3;     // staging: 16 rows/gll, 4 slots/row
    const _Float16* BtU = (EPI == 2) ? Bt + ((size_t)(bm >> 12) << 20) : Bt;  // per-batch B

    int aoff[8], boff[4];
#pragma unroll
    for (int m = 0; m < 8; m++) {
        int r = wm + m * 16 + r15;
        aoff[m] = r * 64 + (((hi + (r >> 1)) & 3) << 4);
    }
#pragma unroll
    for (int n = 0; n < 4; n++) {
        int r = wn + n * 16 + r15;
        boff[n] = r * 64 + (((hi + (r >> 1)) & 3) << 4);
    }

    f32x4 acc[8][4];
#pragma unroll
    for (int m = 0; m < 8; m++)
#pragma unroll
        for (int n = 0; n < 4; n++) acc[m][n] = (f32x4){0.f, 0.f, 0.f, 0.f};

    auto stage = [&](int s) {
        char* base = lds + (s & 3) * 32768;
        int kt = s * 32;
#pragma unroll
        for (int p = 0; p < 2; p++) {
            int row = w * 32 + p * 16 + srow;
            int sg = (sp - ((row >> 1) & 3)) & 3;   // pre-swizzled global slot
            GLL16(A   + (size_t)(bm + row) * K + kt + sg * 8, base + w * 2048 + p * 1024);
            GLL16(BtU + (size_t)(bn + row) * K + kt + sg * 8, base + 16384 + w * 2048 + p * 1024);
        }
    };

    const int NS = K >> 5;
    stage(0); stage(1); stage(2);
    for (int s = 0; s < NS; ++s) {
        if (s + 2 < NS)      asm volatile("s_waitcnt vmcnt(8)" ::: "memory");
        else if (s + 1 < NS) asm volatile("s_waitcnt vmcnt(4)" ::: "memory");
        else                 asm volatile("s_waitcnt vmcnt(0)" ::: "memory");
        asm volatile("s_barrier" ::: "memory");
        if (s + 3 < NS) stage(s + 3);               // slot (s-1)&3: reads done last slab
        const char* La = lds + (s & 3) * 32768;
        const char* Lb = La + 16384;
        f16x8 bv[4];
#pragma unroll
        for (int n = 0; n < 4; n++) bv[n] = *(const f16x8*)(Lb + boff[n]);
        f16x8 av[8];
#pragma unroll
        for (int m = 0; m < 8; m++) av[m] = *(const f16x8*)(La + aoff[m]);
        __builtin_amdgcn_s_setprio(1);
#pragma unroll
        for (int m = 0; m < 8; m++)
#pragma unroll
            for (int n = 0; n < 4; n++)
                acc[m][n] = __builtin_amdgcn_mfma_f32_16x16x32_f16(av[m], bv[n], acc[m][n], 0, 0, 0);
        __builtin_amdgcn_s_setprio(0);
    }

    if (EPI == 5) {
        // cols are head-interleaved [K_h|V_h]; quadrant q = w>>1: 0=K(g0) 1=V(g0) 2=K(g0+1) 3=V(g0+1)
        const int q = w >> 1;
        const bool isK = !(q & 1);
        const int nb = bm >> 12;
        const int g0 = bn >> 7;                 // first local head of this block's pair
        __syncthreads();                        // all slab reads done before LDS reuse
        char* LT = lds + q * 32768;             // tile [64 rows][512 B] (l-major within row)
        float cs[4] = {0.f, 0.f, 0.f, 0.f};
#pragma unroll
        for (int m = 0; m < 8; m++)
#pragma unroll
            for (int n = 0; n < 4; n++) {
                int dd = n * 16 + r15;
                float bs = bias[bn + wn + dd];
                f16x4 pk;
#pragma unroll
                for (int j = 0; j < 4; j++) {
                    float xv = acc[m][n][j] + bs;
                    if (isK) { xv = fmaxf(xv, 0.f) + EPSF; cs[n] += xv; }
                    pk[j] = (_Float16)xv;
                }
                int l2 = (wm + m * 16 + hi * 4) * 2;
                *(f16x4*)(LT + dd * 512 + (l2 ^ ((dd & 7) << 4))) = pk;
            }
        if (isK) {   // fused ksum: this wave covers 128 l-rows of head g0+(q>>1)
#pragma unroll
            for (int n = 0; n < 4; n++) {
                cs[n] += __shfl_xor(cs[n], 16, 64);
                cs[n] += __shfl_xor(cs[n], 32, 64);
            }
            if (hi == 0) {
#pragma unroll
                for (int n = 0; n < 4; n++)
                    atomicAdd(ksum + (size_t)(nb * 16 + g0 + (q >> 1)) * 64 + n * 16 + r15, cs[n]);
            }
        }
        __syncthreads();
        // mini-GEMM kv[d][e] = sum_l Kphi[l][d]*V[l][e] over this block's 256 rows.
        // 32 output 16x16 tiles (2 heads x 4x4); wave w owns tiles w*4 .. w*4+3.
        f32x4 kva[4];
#pragma unroll
        for (int i = 0; i < 4; i++) kva[i] = (f32x4){0.f, 0.f, 0.f, 0.f};
#pragma unroll
        for (int i = 0; i < 4; i++) {
            int tt = w * 4 + i;
            int hl = tt >> 4, dg = (tt >> 2) & 3, eg = tt & 3;
            const char* KT = lds + (hl * 2) * 32768;
            const char* VT = lds + (hl * 2 + 1) * 32768;
            int d = dg * 16 + r15, e = eg * 16 + r15;
#pragma unroll
            for (int ks = 0; ks < 8; ks++) {
                int l2 = (ks * 32 + hi * 8) * 2;
                f16x8 ka = *(const f16x8*)(KT + d * 512 + (l2 ^ ((d & 7) << 4)));
                f16x8 vb = *(const f16x8*)(VT + e * 512 + (l2 ^ ((e & 7) << 4)));
                kva[i] = __builtin_amdgcn_mfma_f32_16x16x32_f16(ka, vb, kva[i], 0, 0, 0);
            }
        }
        const int chunk = (bm >> 8) & 15;
        float* kvp = (float*)out0;
#pragma unroll
        for (int i = 0; i < 4; i++) {
            int tt = w * 4 + i;
            int hl = tt >> 4, dg = (tt >> 2) & 3, eg = tt & 3;
            float* dst = kvp + ((size_t)(nb * 16 + g0 + hl) * 16 + chunk) * 4096;
#pragma unroll
            for (int j = 0; j < 4; j++)
                dst[(dg * 16 + hi * 4 + j) * 64 + eg * 16 + r15] = kva[i][j];
        }
    } else if (EPI == 4) {
        // relu+eps, then divide by den = qphi . ksum[head] (wave owns one head's 64 cols)
        const int headg = (bm >> 12) * 16 + ((bn + wn) >> 6);
        const float* ks = (const float*)out1;
        float ksn[4];
#pragma unroll
        for (int n = 0; n < 4; n++) ksn[n] = ks[(size_t)headg * 64 + n * 16 + r15];
        _Float16* C = (_Float16*)out0;
#pragma unroll
        for (int m = 0; m < 8; m++) {
            int row0 = bm + wm + m * 16 + hi * 4;
            float qv[4][4], dp[4] = {0.f, 0.f, 0.f, 0.f};
#pragma unroll
            for (int n = 0; n < 4; n++) {
                int colg = bn + wn + n * 16 + r15;
                float bs = bias[colg];
#pragma unroll
                for (int j = 0; j < 4; j++) {
                    float xv = fmaxf(acc[m][n][j] + bs, 0.f) + EPSF;
                    qv[n][j] = xv;
                    dp[j] += xv * ksn[n];
                }
            }
#pragma unroll
            for (int j = 0; j < 4; j++) {       // reduce over the 16 r15 lanes
                dp[j] += __shfl_xor(dp[j], 1, 64);
                dp[j] += __shfl_xor(dp[j], 2, 64);
                dp[j] += __shfl_xor(dp[j], 4, 64);
                dp[j] += __shfl_xor(dp[j], 8, 64);
                dp[j] = 4096.0f * __builtin_amdgcn_rcpf(dp[j]);
            }
#pragma unroll
            for (int n = 0; n < 4; n++) {
                int colg = bn + wn + n * 16 + r15;
#pragma unroll
                for (int j = 0; j < 4; j++)
                    C[(size_t)(row0 + j) * N + colg] = (_Float16)(qv[n][j] * dp[j]);
            }
        }
    } else {
#pragma unroll
        for (int m = 0; m < 8; m++) {
            int row0 = bm + wm + m * 16 + hi * 4;
#pragma unroll
            for (int n = 0; n < 4; n++) {
                int colg = bn + wn + n * 16 + r15;
                float bs = bias ? bias[colg] : 0.f;
#pragma unroll
                for (int j = 0; j < 4; j++)
                    ((float*)out0)[(size_t)(row0 + j) * N + colg] = acc[m][n][j] + bs;
            }
        }
    }
}

// ---------------- reduce 16 chunks -> kvT[head][d][e]  (wide grid: 16 slices x 64 heads) ----------------
__global__ __launch_bounds__(256) void kvred(const float* __restrict__ kvpart,
                                             float* __restrict__ kvT) {
    const int sl = blockIdx.x;       // 0..15 slice
    const int gh = blockIdx.y;       // 0..63 head
    const int idx = sl * 256 + threadIdx.x;
    const float* kp = kvpart + (size_t)gh * 16 * 4096 + idx;
    float s = 0.f;
#pragma unroll
    for (int c = 0; c < 16; c++) s += kp[c * 4096];
    kvT[(size_t)gh * 4096 + idx] = s;
}

// ---------------- W2t[b][j][hl*64+d] = (1/4096) sum_e Wot[j][hl*64+e] * kv[gh][d][e] ----------------
// kvT layout is [d][e]; store TRANSPOSED into kvL so kvL[e][d] = kv[d][e].
__global__ __launch_bounds__(256) void w2t_kernel(const _Float16* __restrict__ Wot,
                                                  const float* __restrict__ kvT,
                                                  _Float16* __restrict__ W2t) {
    const int t = threadIdx.x;
    const int jb = blockIdx.x;      // 0..7 (128 j-rows each)
    const int gh = blockIdx.y;      // 0..63 global head
    const int b = gh >> 4, hl = gh & 15;
    __shared__ float kvL[64][65];
    const float* kp = kvT + (size_t)gh * 4096;
#pragma unroll
    for (int i = 0; i < 16; i++) {
        int idx = i * 256 + t;
        kvL[idx & 63][idx >> 6] = kp[idx];   // kvL[e][d] = kv[d][e]
    }
    __syncthreads();
    const int j = jb * 128 + (t >> 1);
    const int d0 = (t & 1) * 32;
    const _Float16* wr = Wot + (size_t)j * 1024 + hl * 64;
    float wv[64];
#pragma unroll
    for (int i = 0; i < 8; i++) {
        f16x8 v = *(const f16x8*)(wr + i * 8);
#pragma unroll
        for (int k = 0; k < 8; k++) wv[i * 8 + k] = (float)v[k];
    }
    _Float16* outp = W2t + ((size_t)b << 20) + (size_t)j * 1024 + hl * 64 + d0;
#pragma unroll
    for (int d = 0; d < 32; d++) {
        float s = 0.f;
#pragma unroll
        for (int e = 0; e < 64; e++) s += wv[e] * kvL[e][d0 + d];
        outp[d] = (_Float16)(s * (1.0f / 4096.0f));
    }
}

// ------------------------------------------------------------------------------------
extern "C" void kernel_launch(void* const* d_in, const int* in_sizes, int n_in,
                              void* d_out, int out_size, void* d_ws, size_t ws_size,
                              hipStream_t stream) {
    (void)in_sizes; (void)n_in; (void)out_size; (void)ws_size;
    const float* x     = (const float*)d_in[0];
    const float* y     = (const float*)d_in[1];
    const float* WQ    = (const float*)d_in[2];
    const float* bQ    = (const float*)d_in[3];
    const float* WK    = (const float*)d_in[4];
    const float* bK    = (const float*)d_in[5];
    const float* WV    = (const float*)d_in[6];
    const float* bV    = (const float*)d_in[7];
    const float* WO    = (const float*)d_in[8];
    const float* bO    = (const float*)d_in[9];
    const float* omega = (const float*)d_in[10];

    char* ws = (char*)d_ws;
    size_t off = 0;
    auto alloc = [&](size_t bytes) { void* p = ws + off; off += (bytes + 255) & ~(size_t)255; return p; };
    const size_t BIG = (size_t)16384 * 1024 * 2;    // 32 MiB f16
    _Float16* xb    = (_Float16*)alloc(BIG);
    _Float16* yb    = (_Float16*)alloc(BIG);
    _Float16* WQKb  = (_Float16*)alloc((size_t)2048 * 1024 * 2);  // stacked WQ;WK f16
    _Float16* obdT  = (_Float16*)alloc(1024 * 1024 * 2);
    _Float16* Wqt   = (_Float16*)alloc(1024 * 1024 * 2);
    _Float16* Wkvt  = (_Float16*)alloc((size_t)2048 * 1024 * 2);  // interleaved rows h*128+[K|V]
    _Float16* Wot   = (_Float16*)alloc(1024 * 1024 * 2);
    _Float16* W2t   = (_Float16*)alloc((size_t)4 * 1024 * 1024 * 2);  // per-batch folded kv@WO (^T)
    float*    bQf   = (float*)alloc(1024 * 4);
    float*    bkv   = (float*)alloc(2048 * 4);
    _Float16* U2    = (_Float16*)alloc(BIG);
    float*    kvpart= (float*)alloc((size_t)64 * 16 * 4096 * 4);  // [head][chunk=16][64][64] (d,e)
    float*    kvT   = (float*)alloc((size_t)64 * 4096 * 4);
    float*    ksum  = (float*)alloc((size_t)64 * 64 * 4);

    // 1. precision converts: x, y, WQ, WK all in one dispatch (17408 blocks covers all items)
    cvt4_f16<<<17408, 256, 0, stream>>>(x, xb, y, yb, WQ, WK, WQKb,
                                        16384 * 1024 / 8, 1024 * 1024 / 8);
    // 2. omega block-diag + interleaved bias folds + ksum zero; both weight transposes in one dispatch
    prep_all<<<4096, 256, 0, stream>>>(omega, bQ, bK, bV, obdT, bQf, bkv, ksum);
    transpose2_cvt<<<dim3(16, 16, 2), 256, 0, stream>>>(WV, Wkvt, WO, Wot);
    // 3. fold omega into WQ/WK (out1 = K-interleaved rows of Wkvt)
    gemm_fold<<<dim3(8, 16), 256, 0, stream>>>(WQKb, obdT, Wqt, Wkvt);
    // 4. K|V projection with fused phi + in-epilogue kv mini-GEMM + ksum atomics
    gemm256<5><<<512, 512, 0, stream>>>(yb, Wkvt, bkv, kvpart, nullptr, ksum, 16384, 2048, 1024, 8);
    // 5. reduce kv chunks (wide grid); fold kv into WO (per batch, scaled 1/4096)
    kvred<<<dim3(16, 64), 256, 0, stream>>>(kvpart, kvT);
    w2t_kernel<<<dim3(8, 64), 256, 0, stream>>>(Wot, kvT, W2t);
    // 6. Q projection with fused phi + divide -> U2 = qphi*4096/den
    gemm256<4><<<256, 512, 0, stream>>>(xb, Wqt, bQf, U2, ksum, nullptr, 16384, 1024, 1024, 4);
    // 7. output projection: out = U2 @ W2t(batch)^T + bO
    gemm256<2><<<256, 512, 0, stream>>>(U2, W2t, bO, d_out, nullptr, nullptr, 16384, 1024, 1024, 4);
}